// Round 5
// baseline (523.893 us; speedup 1.0000x reference)
//
#include <hip/hip_runtime.h>

typedef float f4 __attribute__((ext_vector_type(4)));

#define NB    1024
#define TT    256
#define EE    100
#define VOCAB 5000
#define GG1   256   // 4*H1
#define GG2   128   // 4*H2
#define RPB   2
#define NTHR  512

__device__ __forceinline__ float fast_sigmoid(float x) {
  return __builtin_amdgcn_rcpf(1.0f + __expf(-x));
}

// ---- K1: emb_zi[v][u*4+g] = b1[g*64+u] + sum_k emb[v][k] * W1[k][g*64+u] ----
// Interleaved gate layout so the LSTM kernel's lane lt = u*4+s loads its own scalar.
__global__ __launch_bounds__(256) void emb_gemm(
    const float* __restrict__ emb, const float* __restrict__ W1,
    const float* __restrict__ b1, float* __restrict__ emb_zi)
{
  __shared__ float sE[8][EE];
  const int j  = threadIdx.x;           // standard column index g*64+u
  const int v0 = blockIdx.x * 8;
  for (int idx = j; idx < 8 * EE; idx += 256) {
    int r = idx / EE, k = idx % EE;
    sE[r][k] = emb[(size_t)(v0 + r) * EE + k];
  }
  __syncthreads();
  float acc[8];
  const float bb = b1[j];
  #pragma unroll
  for (int r = 0; r < 8; ++r) acc[r] = bb;
  for (int k = 0; k < EE; ++k) {
    float w = W1[k * GG1 + j];
    #pragma unroll
    for (int r = 0; r < 8; ++r) acc[r] = fmaf(sE[r][k], w, acc[r]);
  }
  const int slot = (j & 63) * 4 + (j >> 6);   // u*4 + g
  #pragma unroll
  for (int r = 0; r < 8; ++r) emb_zi[(size_t)(v0 + r) * GG1 + slot] = acc[r];
}

// Fused gate activation + cell/hidden update for one unit (quad-cooperative).
// On entry lanes of the quad hold identical reduced gate sums (a_i,a_f,a_g,a_o).
// Lane sg activates gate sg (i,f,g,o); 3 shuffles assemble c_new and h_new.
// c is authoritative in lane sg==1; h written by lane with wr==true (sg==3).
__device__ __forceinline__ void gate_update(
    float a_i, float a_f, float a_g, float a_o, float zadd, int sg, bool m,
    float& c, float* hw, const float* hr, bool wr)
{
  float z = (sg == 0) ? a_i : (sg == 1) ? a_f : (sg == 2) ? a_g : a_o;
  z += zadd;
  const bool th = (sg == 2);
  float e = __expf(th ? 2.0f * z : -z);
  float r = __builtin_amdgcn_rcpf(1.0f + e);
  float v = th ? (1.0f - 2.0f * r) : r;          // lane: i,f,g,o
  float ig = v * __shfl_xor(v, 2);               // lane0: i*g
  float fc = v * c;                              // lane1: f*c
  float cn = fc + __shfl_xor(ig, 1);             // lane1: c_new
  float cu = m ? cn : c;
  c = cu;
  float e2 = __expf(2.0f * cu);
  float tc = 1.0f - 2.0f * __builtin_amdgcn_rcpf(1.0f + e2);  // lane1: tanh(c_new)
  float hn = v * __shfl_xor(tc, 2);              // lane3: o * tanh(c_new)
  float ho = m ? hn : *hr;
  if (wr) *hw = ho;
}

// ---- K2: persistent 2-layer LSTM, wave-specialized pipeline, 1 barrier/step ----
// Waves 0-3 (L1): lane (u,s)=(lt>>2, lt&3): unit u, k-quarter s. 64 weight regs.
// Waves 4-7 (L2): lane (u2,s2)=(lt>>3, lt&7): unit u2, k-eighth s2. 48 weight regs.
// L2 runs one step behind L1; sH1/sH2 double-buffered by step parity.
__global__ __launch_bounds__(NTHR) __attribute__((amdgpu_waves_per_eu(4, 4)))
void lstm_fused(
    const int* __restrict__ tokens, const float* __restrict__ emb_zi,
    const float* __restrict__ U1,
    const float* __restrict__ W2, const float* __restrict__ U2, const float* __restrict__ b2,
    const float* __restrict__ Wd, const float* __restrict__ bd,
    float* __restrict__ out)
{
  __shared__ __align__(16) float sH1[2][RPB][64];
  __shared__ __align__(16) float sH2[2][RPB][32];
  __shared__ int sTok[RPB][TT];

  const int tid  = threadIdx.x;
  const int row0 = blockIdx.x * RPB;
  const bool L2g = (tid >= 256);
  const int  lt  = tid & 255;
  const int  u   = lt >> 2;            // L1 unit
  const int  s   = lt & 3;             // L1 k-quarter
  const int  u2  = lt >> 3;            // L2 unit
  const int  s2  = lt & 7;             // L2 k-eighth
  const int  sg  = lt & 3;             // lane's gate (same for both groups)

  // ---- weights into registers (union array: L1 uses 16 f4, L2 uses 12) ----
  f4 wU[16];
  float biasg = 0.0f;
  if (!L2g) {
    #pragma unroll
    for (int kk = 0; kk < 16; ++kk) {
      int k = 16 * s + kk;
      f4 w;
      w[0] = U1[k * GG1 + u];
      w[1] = U1[k * GG1 + 64 + u];
      w[2] = U1[k * GG1 + 128 + u];
      w[3] = U1[k * GG1 + 192 + u];
      wU[kk] = w;
    }
  } else {
    #pragma unroll
    for (int kk = 0; kk < 12; ++kk) {
      int k = 12 * s2 + kk;            // 0..63 -> W2 row k; 64..95 -> U2 row k-64
      const float* src = (k < 64) ? &W2[(size_t)k * GG2] : &U2[(size_t)(k - 64) * GG2];
      f4 w;
      w[0] = src[u2]; w[1] = src[32 + u2]; w[2] = src[64 + u2]; w[3] = src[96 + u2];
      wU[kk] = w;
    }
    biasg = b2[sg * 32 + u2];
  }

  // ---- one-time LDS init ----
  {
    int r = tid >> 8, t = tid & (TT - 1);
    sTok[r][t] = tokens[(size_t)(row0 + r) * TT + t];
  }
  if (tid < 128)      sH1[0][tid >> 6][tid & 63] = 0.0f;
  else if (tid < 192) { int x = tid - 128; sH2[0][x >> 5][x & 31] = 0.0f; }
  float c0 = 0.0f, c1 = 0.0f;          // cell state per row (authoritative at sg==1)
  __syncthreads();

  // ---- zx prologue (L1 lanes): lane lt reads its own interleaved scalar ----
  float zxc0 = 0.f, zxc1 = 0.f, zxn0 = 0.f, zxn1 = 0.f;
  if (!L2g) {
    zxc0 = emb_zi[(size_t)sTok[0][0] * GG1 + lt];
    zxc1 = emb_zi[(size_t)sTok[1][0] * GG1 + lt];
  }

  for (int i = 0; i <= TT; ++i) {
    if (!L2g) {
      if (i < TT) {                                 // L1 step t = i
        if (i + 1 < TT) {                           // prefetch z_x(t+1)
          zxn0 = emb_zi[(size_t)sTok[0][i + 1] * GG1 + lt];
          zxn1 = emb_zi[(size_t)sTok[1][i + 1] * GG1 + lt];
        }
        const int rb = i & 1, wb = rb ^ 1;
        float ai0=0,af0=0,ag0=0,ao0=0, ai1=0,af1=0,ag1=0,ao1=0;
        const f4* h0p = (const f4*)&sH1[rb][0][16 * s];
        const f4* h1p = (const f4*)&sH1[rb][1][16 * s];
        #pragma unroll
        for (int q = 0; q < 4; ++q) {
          f4 h0 = h0p[q], h1 = h1p[q];
          #pragma unroll
          for (int kk = 0; kk < 4; ++kk) {
            f4 w = wU[4 * q + kk];
            ai0 = fmaf(h0[kk], w[0], ai0); af0 = fmaf(h0[kk], w[1], af0);
            ag0 = fmaf(h0[kk], w[2], ag0); ao0 = fmaf(h0[kk], w[3], ao0);
            ai1 = fmaf(h1[kk], w[0], ai1); af1 = fmaf(h1[kk], w[1], af1);
            ag1 = fmaf(h1[kk], w[2], ag1); ao1 = fmaf(h1[kk], w[3], ao1);
          }
        }
        // quad butterfly: every lane gets all 4 gate totals
        ai0 += __shfl_xor(ai0,1); af0 += __shfl_xor(af0,1); ag0 += __shfl_xor(ag0,1); ao0 += __shfl_xor(ao0,1);
        ai0 += __shfl_xor(ai0,2); af0 += __shfl_xor(af0,2); ag0 += __shfl_xor(ag0,2); ao0 += __shfl_xor(ao0,2);
        ai1 += __shfl_xor(ai1,1); af1 += __shfl_xor(af1,1); ag1 += __shfl_xor(ag1,1); ao1 += __shfl_xor(ao1,1);
        ai1 += __shfl_xor(ai1,2); af1 += __shfl_xor(af1,2); ag1 += __shfl_xor(ag1,2); ao1 += __shfl_xor(ao1,2);
        const bool m0 = (sTok[0][i] != 0), m1 = (sTok[1][i] != 0);
        gate_update(ai0, af0, ag0, ao0, zxc0, sg, m0, c0,
                    &sH1[wb][0][u], &sH1[rb][0][u], sg == 3);
        gate_update(ai1, af1, ag1, ao1, zxc1, sg, m1, c1,
                    &sH1[wb][1][u], &sH1[rb][1][u], sg == 3);
        zxc0 = zxn0; zxc1 = zxn1;
      }
    } else {
      if (i >= 1) {                                 // L2 step tt = i-1
        const int tt = i - 1;
        const int rbh1 = i & 1;                     // buffer holding h1(tt)
        const int rbh2 = tt & 1, wbh2 = rbh2 ^ 1;
        float ai0=0,af0=0,ag0=0,ao0=0, ai1=0,af1=0,ag1=0,ao1=0;
        #pragma unroll
        for (int q = 0; q < 3; ++q) {
          int k = 12 * s2 + 4 * q;
          const f4* p0 = (k < 64) ? (const f4*)&sH1[rbh1][0][k]
                                  : (const f4*)&sH2[rbh2][0][k - 64];
          const f4* p1 = (k < 64) ? (const f4*)&sH1[rbh1][1][k]
                                  : (const f4*)&sH2[rbh2][1][k - 64];
          f4 h0 = *p0, h1 = *p1;
          #pragma unroll
          for (int kk = 0; kk < 4; ++kk) {
            f4 w = wU[4 * q + kk];
            ai0 = fmaf(h0[kk], w[0], ai0); af0 = fmaf(h0[kk], w[1], af0);
            ag0 = fmaf(h0[kk], w[2], ag0); ao0 = fmaf(h0[kk], w[3], ao0);
            ai1 = fmaf(h1[kk], w[0], ai1); af1 = fmaf(h1[kk], w[1], af1);
            ag1 = fmaf(h1[kk], w[2], ag1); ao1 = fmaf(h1[kk], w[3], ao1);
          }
        }
        // octet butterfly (xor4 first, then quad): all 8 lanes get all totals
        ai0 += __shfl_xor(ai0,4); af0 += __shfl_xor(af0,4); ag0 += __shfl_xor(ag0,4); ao0 += __shfl_xor(ao0,4);
        ai0 += __shfl_xor(ai0,1); af0 += __shfl_xor(af0,1); ag0 += __shfl_xor(ag0,1); ao0 += __shfl_xor(ao0,1);
        ai0 += __shfl_xor(ai0,2); af0 += __shfl_xor(af0,2); ag0 += __shfl_xor(ag0,2); ao0 += __shfl_xor(ao0,2);
        ai1 += __shfl_xor(ai1,4); af1 += __shfl_xor(af1,4); ag1 += __shfl_xor(ag1,4); ao1 += __shfl_xor(ao1,4);
        ai1 += __shfl_xor(ai1,1); af1 += __shfl_xor(af1,1); ag1 += __shfl_xor(ag1,1); ao1 += __shfl_xor(ao1,1);
        ai1 += __shfl_xor(ai1,2); af1 += __shfl_xor(af1,2); ag1 += __shfl_xor(ag1,2); ao1 += __shfl_xor(ao1,2);
        const bool m0 = (sTok[0][tt] != 0), m1 = (sTok[1][tt] != 0);
        gate_update(ai0, af0, ag0, ao0, biasg, sg, m0, c0,
                    &sH2[wbh2][0][u2], &sH2[rbh2][0][u2], s2 == 3);
        gate_update(ai1, af1, ag1, ao1, biasg, sg, m1, c1,
                    &sH2[wbh2][1][u2], &sH2[rbh2][1][u2], s2 == 3);
      }
    }
    __syncthreads();
  }

  // ---- epilogue: out = sigmoid(h2 @ Wd + bd); final h2 is in buffer 0 ----
  if (tid < RPB * 4) {
    int r = tid >> 2, o = tid & 3;
    float a = bd[o];
    #pragma unroll
    for (int kk = 0; kk < 32; ++kk)
      a = fmaf(sH2[0][r][kk], Wd[kk * 4 + o], a);
    out[(size_t)(row0 + r) * 4 + o] = fast_sigmoid(a);
  }
}

extern "C" void kernel_launch(void* const* d_in, const int* in_sizes, int n_in,
                              void* d_out, int out_size, void* d_ws, size_t ws_size,
                              hipStream_t stream) {
  const int*   tokens = (const int*)d_in[0];
  const float* emb    = (const float*)d_in[1];
  const float* W1     = (const float*)d_in[2];
  const float* U1     = (const float*)d_in[3];
  const float* b1     = (const float*)d_in[4];
  const float* W2     = (const float*)d_in[5];
  const float* U2     = (const float*)d_in[6];
  const float* b2     = (const float*)d_in[7];
  const float* Wd     = (const float*)d_in[8];
  const float* bd     = (const float*)d_in[9];
  float* out    = (float*)d_out;
  float* emb_zi = (float*)d_ws;         // 5000*256*4 = 5.12 MB scratch

  emb_gemm<<<dim3(VOCAB / 8), dim3(256), 0, stream>>>(emb, W1, b1, emb_zi);
  lstm_fused<<<dim3(NB / RPB), dim3(NTHR), 0, stream>>>(
      tokens, emb_zi, U1, W2, U2, b2, Wd, bd, out);
}

// Round 6
// 322.946 us; speedup vs baseline: 1.6222x; 1.6222x over previous
//
#include <hip/hip_runtime.h>

typedef float f4 __attribute__((ext_vector_type(4)));

#define NB    1024
#define TT    256
#define EE    100
#define VOCAB 5000
#define GG1   256   // 4*H1
#define GG2   128   // 4*H2
#define RPB   2
#define NTHR  512

__device__ __forceinline__ float fast_sigmoid(float x) {
  return __builtin_amdgcn_rcpf(1.0f + __expf(-x));
}

// quad_perm DPP cross-lane (VALU pipe, no LDS): 0xB1 = xor1, 0x4E = xor2
template <int CTRL>
__device__ __forceinline__ float dppq(float x) {
  return __int_as_float(
      __builtin_amdgcn_mov_dpp(__float_as_int(x), CTRL, 0xF, 0xF, true));
}
__device__ __forceinline__ float swz_xor4(float x) {  // lane ^= 4 (LDS pipe)
  return __int_as_float(__builtin_amdgcn_ds_swizzle(__float_as_int(x), 0x101F));
}

// Reduce 4 gate-accumulators across a quad; lane sg (=lane&3) returns gate sg's sum.
__device__ __forceinline__ float qredsel(float ai, float af, float ag, float ao, int sg) {
  ai += dppq<0xB1>(ai); af += dppq<0xB1>(af);
  ag += dppq<0xB1>(ag); ao += dppq<0xB1>(ao);
  float pl = (sg & 1) ? af : ai;     // gate (bit0 ? f : i), partial over pairs
  float ph = (sg & 1) ? ao : ag;     // gate (bit0 ? o : g)
  pl += dppq<0x4E>(pl); ph += dppq<0x4E>(ph);
  return (sg & 2) ? ph : pl;         // lane sg holds gate sg's 4-lane sum
}

// Quad-cooperative activation + state update. z = pre-activation for gate sg
// (full k-sum, bias included). c authoritative on lane sg==1; h on lane sg==3.
__device__ __forceinline__ void gate_up(float z, int sg, bool m, float& c, float& h) {
  const bool th = (sg == 2);
  float e = __expf(th ? 2.0f * z : -z);
  float r = __builtin_amdgcn_rcpf(1.0f + e);
  float v = th ? (1.0f - 2.0f * r) : r;            // lanes: i, f, g, o
  float ig = v * dppq<0x4E>(v);                    // lane0: i*g
  float fc = v * c;                                // lane1: f*c
  float cn = fc + dppq<0xB1>(ig);                  // lane1: c_new
  float cu = m ? cn : c;
  c = cu;
  float e2 = __expf(2.0f * cu);
  float tc = 1.0f - 2.0f * __builtin_amdgcn_rcpf(1.0f + e2);  // lane1: tanh(c)
  float hn = v * dppq<0x4E>(tc);                   // lane3: o*tanh(c)
  if (m) h = hn;                                   // lane3 carries h in-register
}

// ---- K1: emb_zi[v][u*4+g] = b1[g*64+u] + sum_k emb[v][k]*W1[k][g*64+u] ----
__global__ __launch_bounds__(256) void emb_gemm(
    const float* __restrict__ emb, const float* __restrict__ W1,
    const float* __restrict__ b1, float* __restrict__ emb_zi)
{
  __shared__ float sE[8][EE];
  const int j  = threadIdx.x;           // column g*64+u
  const int v0 = blockIdx.x * 8;
  for (int idx = j; idx < 8 * EE; idx += 256) {
    int r = idx / EE, k = idx % EE;
    sE[r][k] = emb[(size_t)(v0 + r) * EE + k];
  }
  __syncthreads();
  float acc[8];
  const float bb = b1[j];
  #pragma unroll
  for (int r = 0; r < 8; ++r) acc[r] = bb;
  for (int k = 0; k < EE; ++k) {
    float w = W1[k * GG1 + j];
    #pragma unroll
    for (int r = 0; r < 8; ++r) acc[r] = fmaf(sE[r][k], w, acc[r]);
  }
  const int slot = (j & 63) * 4 + (j >> 6);   // u*4 + g
  #pragma unroll
  for (int r = 0; r < 8; ++r) emb_zi[(size_t)(v0 + r) * GG1 + slot] = acc[r];
}

// ---- K2: persistent 2-layer LSTM; wave-specialized; 1 barrier/step ----
// Unified h-buffer sHC[parity][row][96]: floats 0..63 = h1, 64..95 = h2.
// At step i: ALL writes -> parity i&1 (L1 writes h1(i), L2 writes h2(i-1));
//            ALL reads  <- parity (i&1)^1 (h1(i-1) and h2(i-2)).
__global__ __launch_bounds__(NTHR) __attribute__((amdgpu_waves_per_eu(4, 4)))
void lstm_fused(
    const int* __restrict__ tokens, const float* __restrict__ emb_zi,
    const float* __restrict__ U1,
    const float* __restrict__ W2, const float* __restrict__ U2, const float* __restrict__ b2,
    const float* __restrict__ Wd, const float* __restrict__ bd,
    float* __restrict__ out)
{
  __shared__ __align__(16) float sHC[2][RPB][96];
  __shared__ int2 sTokP[TT];

  const int tid  = threadIdx.x;
  const int row0 = blockIdx.x * RPB;
  const bool L2g = (tid >= 256);
  const int  lt  = tid & 255;
  const int  u   = lt >> 2;            // L1 unit (0..63)
  const int  sg  = lt & 3;             // gate id within quad
  const int  u2  = lt >> 3;            // L2 unit (0..31)
  const int  s2  = lt & 7;             // L2 k-eighth

  // ---- weights into registers ----
  f4 wU[16];
  float biasg = 0.0f;
  if (!L2g) {
    #pragma unroll
    for (int kk = 0; kk < 16; ++kk) {
      int k = 16 * sg + kk;            // quad lane sg owns k-quarter sg
      f4 w;
      w[0] = U1[k * GG1 + u];
      w[1] = U1[k * GG1 + 64 + u];
      w[2] = U1[k * GG1 + 128 + u];
      w[3] = U1[k * GG1 + 192 + u];
      wU[kk] = w;
    }
    asm volatile("" : "+v"(wU[0]), "+v"(wU[1]), "+v"(wU[2]), "+v"(wU[3]),
                      "+v"(wU[4]), "+v"(wU[5]), "+v"(wU[6]), "+v"(wU[7]),
                      "+v"(wU[8]), "+v"(wU[9]), "+v"(wU[10]), "+v"(wU[11]),
                      "+v"(wU[12]), "+v"(wU[13]), "+v"(wU[14]), "+v"(wU[15]));
  } else {
    #pragma unroll
    for (int kk = 0; kk < 12; ++kk) {
      int k = 12 * s2 + kk;            // 0..63 -> W2 row k; 64..95 -> U2 row k-64
      const float* src = (k < 64) ? &W2[(size_t)k * GG2] : &U2[(size_t)(k - 64) * GG2];
      f4 w;
      w[0] = src[u2]; w[1] = src[32 + u2]; w[2] = src[64 + u2]; w[3] = src[96 + u2];
      wU[kk] = w;
    }
    asm volatile("" : "+v"(wU[0]), "+v"(wU[1]), "+v"(wU[2]), "+v"(wU[3]),
                      "+v"(wU[4]), "+v"(wU[5]), "+v"(wU[6]), "+v"(wU[7]),
                      "+v"(wU[8]), "+v"(wU[9]), "+v"(wU[10]), "+v"(wU[11]));
    biasg = b2[sg * 32 + u2];
  }

  // ---- one-time LDS init ----
  if (tid < TT)
    sTokP[tid] = make_int2(tokens[(size_t)row0 * TT + tid],
                           tokens[(size_t)(row0 + 1) * TT + tid]);
  if (tid < 2 * RPB * 96) ((float*)sHC)[tid] = 0.0f;
  float c0 = 0.0f, c1 = 0.0f;          // cell state per row (lane sg==1)
  float h0r = 0.0f, h1r = 0.0f;        // hidden per row (lane sg==3 / s2==3)
  __syncthreads();

  // ---- prologue (L1 lanes): token pair + z_x for t=0 ----
  int2  tokc = make_int2(0, 0);
  float zxc0 = 0.f, zxc1 = 0.f;
  if (!L2g) {
    tokc = sTokP[0];
    zxc0 = emb_zi[(size_t)tokc.x * GG1 + lt];
    zxc1 = emb_zi[(size_t)tokc.y * GG1 + lt];
  }

  for (int i = 0; i <= TT; ++i) {
    const int rbuf = (i & 1) ^ 1, wbuf = i & 1;
    if (!L2g) {
      if (i < TT) {                                 // L1 step t = i
        const bool m0 = (tokc.x != 0), m1 = (tokc.y != 0);
        int2 tokn = make_int2(0, 0);
        float zxn0 = 0.f, zxn1 = 0.f;
        if (i + 1 < TT) {                           // prefetch z_x(t+1)
          tokn = sTokP[i + 1];
          zxn0 = emb_zi[(size_t)tokn.x * GG1 + lt];
          zxn1 = emb_zi[(size_t)tokn.y * GG1 + lt];
        }
        const f4* h0p = (const f4*)&sHC[rbuf][0][16 * sg];
        const f4* h1p = (const f4*)&sHC[rbuf][1][16 * sg];
        float ai0=0,af0=0,ag0=0,ao0=0, ai1=0,af1=0,ag1=0,ao1=0;
        #pragma unroll
        for (int q = 0; q < 4; ++q) {
          f4 h0 = h0p[q], h1 = h1p[q];
          #pragma unroll
          for (int kk = 0; kk < 4; ++kk) {
            f4 w = wU[4 * q + kk];
            ai0 = fmaf(h0[kk], w[0], ai0); af0 = fmaf(h0[kk], w[1], af0);
            ag0 = fmaf(h0[kk], w[2], ag0); ao0 = fmaf(h0[kk], w[3], ao0);
            ai1 = fmaf(h1[kk], w[0], ai1); af1 = fmaf(h1[kk], w[1], af1);
            ag1 = fmaf(h1[kk], w[2], ag1); ao1 = fmaf(h1[kk], w[3], ao1);
          }
        }
        float z0 = qredsel(ai0, af0, ag0, ao0, sg) + zxc0;
        float z1 = qredsel(ai1, af1, ag1, ao1, sg) + zxc1;
        gate_up(z0, sg, m0, c0, h0r);
        gate_up(z1, sg, m1, c1, h1r);
        if (sg == 3) { sHC[wbuf][0][u] = h0r; sHC[wbuf][1][u] = h1r; }
        tokc = tokn; zxc0 = zxn0; zxc1 = zxn1;
      }
    } else {
      if (i >= 1) {                                 // L2 step tt = i-1
        const int tt = i - 1;
        int2 tk = sTokP[tt];
        const bool m0 = (tk.x != 0), m1 = (tk.y != 0);
        const f4* h0p = (const f4*)&sHC[rbuf][0][12 * s2];
        const f4* h1p = (const f4*)&sHC[rbuf][1][12 * s2];
        float ai0=0,af0=0,ag0=0,ao0=0, ai1=0,af1=0,ag1=0,ao1=0;
        #pragma unroll
        for (int q = 0; q < 3; ++q) {
          f4 h0 = h0p[q], h1 = h1p[q];
          #pragma unroll
          for (int kk = 0; kk < 4; ++kk) {
            f4 w = wU[4 * q + kk];
            ai0 = fmaf(h0[kk], w[0], ai0); af0 = fmaf(h0[kk], w[1], af0);
            ag0 = fmaf(h0[kk], w[2], ag0); ao0 = fmaf(h0[kk], w[3], ao0);
            ai1 = fmaf(h1[kk], w[0], ai1); af1 = fmaf(h1[kk], w[1], af1);
            ag1 = fmaf(h1[kk], w[2], ag1); ao1 = fmaf(h1[kk], w[3], ao1);
          }
        }
        float q0 = qredsel(ai0, af0, ag0, ao0, sg);
        float q1 = qredsel(ai1, af1, ag1, ao1, sg);
        float z0 = q0 + swz_xor4(q0) + biasg;       // full 8-lane k-sum
        float z1 = q1 + swz_xor4(q1) + biasg;
        gate_up(z0, sg, m0, c0, h0r);
        gate_up(z1, sg, m1, c1, h1r);
        if (s2 == 3) { sHC[wbuf][0][64 + u2] = h0r; sHC[wbuf][1][64 + u2] = h1r; }
      }
    }
    __syncthreads();
  }

  // ---- epilogue: out = sigmoid(h2 @ Wd + bd); final h2 in parity TT&1 = 0 ----
  if (tid < RPB * 4) {
    int r = tid >> 2, o = tid & 3;
    float a = bd[o];
    #pragma unroll
    for (int kk = 0; kk < 32; ++kk)
      a = fmaf(sHC[0][r][64 + kk], Wd[kk * 4 + o], a);
    out[(size_t)(row0 + r) * 4 + o] = fast_sigmoid(a);
  }
}

extern "C" void kernel_launch(void* const* d_in, const int* in_sizes, int n_in,
                              void* d_out, int out_size, void* d_ws, size_t ws_size,
                              hipStream_t stream) {
  const int*   tokens = (const int*)d_in[0];
  const float* emb    = (const float*)d_in[1];
  const float* W1     = (const float*)d_in[2];
  const float* U1     = (const float*)d_in[3];
  const float* b1     = (const float*)d_in[4];
  const float* W2     = (const float*)d_in[5];
  const float* U2     = (const float*)d_in[6];
  const float* b2     = (const float*)d_in[7];
  const float* Wd     = (const float*)d_in[8];
  const float* bd     = (const float*)d_in[9];
  float* out    = (float*)d_out;
  float* emb_zi = (float*)d_ws;         // 5000*256*4 = 5.12 MB scratch

  emb_gemm<<<dim3(VOCAB / 8), dim3(256), 0, stream>>>(emb, W1, b1, emb_zi);
  lstm_fused<<<dim3(NB / RPB), dim3(NTHR), 0, stream>>>(
      tokens, emb_zi, U1, W2, U2, b2, Wd, bd, out);
}